// Round 1
// baseline (582.494 us; speedup 1.0000x reference)
//
#include <hip/hip_runtime.h>
#include <math.h>

#define NQ 8192   // queries
#define MK 8192   // keys
#define CD 512    // embed dim
#define LN 64     // neighbors per query
#define HH 8      // heads
#define HD 64     // head dim
#define BB 16     // batches

// ---------------------------------------------------------------------------
// NT GEMM body: out[i][j] = (sum_k A[i][k]*W[j][k] + bias[j]) * scale
// A: rows x CD row-major; W: CD x CD row-major (row j is output col j).
// 64x64 tile, BK=16, 256 threads, each thread 4x4 outputs.
// ---------------------------------------------------------------------------
__device__ __forceinline__ void gemm_nt_body(const float* __restrict__ A,
                                             const float* __restrict__ W,
                                             const float* __restrict__ bias,
                                             float* __restrict__ out,
                                             float scale) {
    __shared__ float As[16][68];   // [k][m], pad 68 keeps float4 alignment per row
    __shared__ float Bs[16][68];
    const int tid  = threadIdx.x;
    const int row0 = blockIdx.x * 64;
    const int col0 = blockIdx.y * 64;
    const int m  = tid >> 2;            // 0..63  (row within tile for staging)
    const int kq = (tid & 3) * 4;       // 0,4,8,12 (k within tile for staging)
    const int tx = tid & 15;            // 0..15 (col group)
    const int ty = tid >> 4;            // 0..15 (row group)

    float c[4][4] = {{0.f, 0.f, 0.f, 0.f}, {0.f, 0.f, 0.f, 0.f},
                     {0.f, 0.f, 0.f, 0.f}, {0.f, 0.f, 0.f, 0.f}};

    const float* Ap = A + (size_t)(row0 + m) * CD + kq;
    const float* Wp = W + (size_t)(col0 + m) * CD + kq;

    for (int k0 = 0; k0 < CD; k0 += 16) {
        float4 av = *(const float4*)(Ap + k0);
        float4 wv = *(const float4*)(Wp + k0);
        As[kq + 0][m] = av.x; As[kq + 1][m] = av.y;
        As[kq + 2][m] = av.z; As[kq + 3][m] = av.w;
        Bs[kq + 0][m] = wv.x; Bs[kq + 1][m] = wv.y;
        Bs[kq + 2][m] = wv.z; Bs[kq + 3][m] = wv.w;
        __syncthreads();
#pragma unroll
        for (int kk = 0; kk < 16; ++kk) {
            float4 a4 = *(const float4*)&As[kk][ty * 4];
            float4 b4 = *(const float4*)&Bs[kk][tx * 4];
            float a[4] = {a4.x, a4.y, a4.z, a4.w};
            float b[4] = {b4.x, b4.y, b4.z, b4.w};
#pragma unroll
            for (int i = 0; i < 4; ++i)
#pragma unroll
                for (int j = 0; j < 4; ++j)
                    c[i][j] = fmaf(a[i], b[j], c[i][j]);
        }
        __syncthreads();
    }

    float4 bb = *(const float4*)&bias[col0 + tx * 4];
    const float bv[4] = {bb.x, bb.y, bb.z, bb.w};
#pragma unroll
    for (int i = 0; i < 4; ++i) {
        const int r = row0 + ty * 4 + i;
        float4 o;
        o.x = (c[i][0] + bv[0]) * scale;
        o.y = (c[i][1] + bv[1]) * scale;
        o.z = (c[i][2] + bv[2]) * scale;
        o.w = (c[i][3] + bv[3]) * scale;
        *(float4*)&out[(size_t)r * CD + col0 + tx * 4] = o;
    }
}

// qkv: z=0 -> q = (query@Wq.T + bq)*0.125 ; z=1 -> k ; z=2 -> v
__global__ __launch_bounds__(256) void qkv_gemm(const float* __restrict__ q_in,
                                                const float* __restrict__ k_in,
                                                const float* __restrict__ v_in,
                                                const float* __restrict__ W,
                                                const float* __restrict__ bias,
                                                float* __restrict__ ws) {
    const int z = blockIdx.z;
    const float* A = (z == 0) ? q_in : ((z == 1) ? k_in : v_in);
    gemm_nt_body(A, W + (size_t)z * CD * CD, bias + (size_t)z * CD,
                 ws + (size_t)z * NQ * CD, (z == 0) ? 0.125f : 1.0f);
}

__global__ __launch_bounds__(256) void out_gemm(const float* __restrict__ A,
                                                const float* __restrict__ W,
                                                const float* __restrict__ bias,
                                                float* __restrict__ out) {
    gemm_nt_body(A, W, bias, out, 1.0f);
}

// ---------------------------------------------------------------------------
// Attention: 1 block per query, 8 waves = 8 heads, lane <-> neighbor (scores)
// then lane <-> head-dim (PV). attn result overwrites the q buffer in place.
// ---------------------------------------------------------------------------
__global__ __launch_bounds__(512) void attn_kernel(
    const float* __restrict__ ws_qkv,            // [q | k | v], each NQ*CD
    const int* __restrict__ index_pair,          // (NQ, LN)
    const int* __restrict__ key_batch_cnt,       // (BB,)
    const int* __restrict__ index_pair_batch,    // (NQ,)
    float* __restrict__ attn_out,                // NQ*CD (aliases q buffer)
    float* __restrict__ out2) {                  // NQ*LN
    const float* q_ws = ws_qkv;
    const float* k_ws = ws_qkv + (size_t)NQ * CD;
    const float* v_ws = ws_qkv + (size_t)2 * NQ * CD;

    const int n    = blockIdx.x;
    const int tid  = threadIdx.x;
    const int h    = tid >> 6;     // wave id = head
    const int lane = tid & 63;

    __shared__ float qs[CD];
    __shared__ float wmat[HH][LN];

    qs[tid] = q_ws[(size_t)n * CD + tid];

    const int batch = index_pair_batch[n];
    int offset = 0;
    for (int b = 0; b < batch; ++b) offset += key_batch_cnt[b];

    const int gi = index_pair[n * LN + lane];
    const bool valid = (gi >= 0);
    const int g = valid ? (gi + offset) : 0;   // matches reference safe-gather

    __syncthreads();

    // --- scores: lane = neighbor -----------------------------------------
    const float4* kp = (const float4*)(k_ws + (size_t)g * CD + h * HD);
    const float4* qp = (const float4*)(qs + h * HD);
    float acc = 0.f;
#pragma unroll
    for (int i = 0; i < 16; ++i) {
        float4 kv = kp[i];
        float4 qv = qp[i];
        acc += kv.x * qv.x + kv.y * qv.y + kv.z * qv.z + kv.w * qv.w;
    }
    float score = valid ? acc : -1000.0f;   // MASK_VAL

    // --- softmax over 64 lanes (full wave) -------------------------------
    float mx = score;
#pragma unroll
    for (int o = 32; o > 0; o >>= 1) mx = fmaxf(mx, __shfl_xor(mx, o, 64));
    float e = __expf(score - mx);           // masked lanes underflow to 0
    float s = e;
#pragma unroll
    for (int o = 32; o > 0; o >>= 1) s += __shfl_xor(s, o, 64);
    const float w = e / s;
    wmat[h][lane] = w;

    // --- PV: lane = head-dim d; broadcast (w_l, g_l) from lane l ---------
    float acc2 = 0.f;
    for (int l = 0; l < LN; ++l) {
        const float wl = __shfl(w, l, 64);
        const int   gl = __shfl(g, l, 64);
        if (wl != 0.f)   // wave-uniform branch (wl broadcast)
            acc2 += wl * v_ws[(size_t)gl * CD + h * HD + lane];
    }
    attn_out[(size_t)n * CD + h * HD + lane] = acc2;

    __syncthreads();
    // --- output 2: sum over heads / H ------------------------------------
    if (tid < LN) {
        float s8 = 0.f;
#pragma unroll
        for (int hh = 0; hh < HH; ++hh) s8 += wmat[hh][tid];
        out2[(size_t)n * LN + tid] = s8 * (1.0f / HH);
    }
}

// ---------------------------------------------------------------------------
extern "C" void kernel_launch(void* const* d_in, const int* in_sizes, int n_in,
                              void* d_out, int out_size, void* d_ws, size_t ws_size,
                              hipStream_t stream) {
    const float* query   = (const float*)d_in[0];
    const float* key     = (const float*)d_in[1];
    const float* value   = (const float*)d_in[2];
    const float* ipw     = (const float*)d_in[3];   // (3C, C)
    const float* ipb     = (const float*)d_in[4];   // (3C,)
    const float* out_w   = (const float*)d_in[5];   // (C, C)
    const float* out_b   = (const float*)d_in[6];   // (C,)
    const int*   index_pair       = (const int*)d_in[7];
    // d_in[8] = query_batch_cnt (unused: implied by index_pair_batch)
    const int*   key_batch_cnt    = (const int*)d_in[9];
    const int*   index_pair_batch = (const int*)d_in[10];

    float* out = (float*)d_out;                // [attn (NQ*CD) | out2 (NQ*LN)]
    float* ws  = (float*)d_ws;                 // [q | k | v], 48 MB

    // 1) q/k/v projections
    dim3 g1(NQ / 64, CD / 64, 3);
    qkv_gemm<<<g1, 256, 0, stream>>>(query, key, value, ipw, ipb, ws);

    // 2) gather attention (attn overwrites q buffer in place) + output 2
    attn_kernel<<<NQ, 512, 0, stream>>>(ws, index_pair, key_batch_cnt,
                                        index_pair_batch, ws,
                                        out + (size_t)NQ * CD);

    // 3) out projection -> output 1
    dim3 g3(NQ / 64, CD / 64, 1);
    out_gemm<<<g3, 256, 0, stream>>>(ws, out_w, out_b, out);
}

// Round 2
// 435.710 us; speedup vs baseline: 1.3369x; 1.3369x over previous
//
#include <hip/hip_runtime.h>
#include <math.h>

#define NQ 8192   // queries
#define MK 8192   // keys
#define CD 512    // embed dim
#define LN 64     // neighbors per query
#define HH 8      // heads
#define HD 64     // head dim
#define BB 16     // batches

// ---------------------------------------------------------------------------
// NT GEMM body: out[i][j] = (sum_k A[i][k]*W[j][k] + bias[j]) * scale
// A: rows x CD row-major; W: CD x CD row-major (row j is output col j).
// 64x64 tile, BK=16, 256 threads, each thread 4x4 outputs.
// ---------------------------------------------------------------------------
__device__ __forceinline__ void gemm_nt_body(const float* __restrict__ A,
                                             const float* __restrict__ W,
                                             const float* __restrict__ bias,
                                             float* __restrict__ out,
                                             float scale) {
    __shared__ float As[16][68];   // [k][m], pad 68 keeps float4 alignment per row
    __shared__ float Bs[16][68];
    const int tid  = threadIdx.x;
    const int row0 = blockIdx.x * 64;
    const int col0 = blockIdx.y * 64;
    const int m  = tid >> 2;            // 0..63  (row within tile for staging)
    const int kq = (tid & 3) * 4;       // 0,4,8,12 (k within tile for staging)
    const int tx = tid & 15;            // 0..15 (col group)
    const int ty = tid >> 4;            // 0..15 (row group)

    float c[4][4] = {{0.f, 0.f, 0.f, 0.f}, {0.f, 0.f, 0.f, 0.f},
                     {0.f, 0.f, 0.f, 0.f}, {0.f, 0.f, 0.f, 0.f}};

    const float* Ap = A + (size_t)(row0 + m) * CD + kq;
    const float* Wp = W + (size_t)(col0 + m) * CD + kq;

    for (int k0 = 0; k0 < CD; k0 += 16) {
        float4 av = *(const float4*)(Ap + k0);
        float4 wv = *(const float4*)(Wp + k0);
        As[kq + 0][m] = av.x; As[kq + 1][m] = av.y;
        As[kq + 2][m] = av.z; As[kq + 3][m] = av.w;
        Bs[kq + 0][m] = wv.x; Bs[kq + 1][m] = wv.y;
        Bs[kq + 2][m] = wv.z; Bs[kq + 3][m] = wv.w;
        __syncthreads();
#pragma unroll
        for (int kk = 0; kk < 16; ++kk) {
            float4 a4 = *(const float4*)&As[kk][ty * 4];
            float4 b4 = *(const float4*)&Bs[kk][tx * 4];
            float a[4] = {a4.x, a4.y, a4.z, a4.w};
            float b[4] = {b4.x, b4.y, b4.z, b4.w};
#pragma unroll
            for (int i = 0; i < 4; ++i)
#pragma unroll
                for (int j = 0; j < 4; ++j)
                    c[i][j] = fmaf(a[i], b[j], c[i][j]);
        }
        __syncthreads();
    }

    float4 bb = *(const float4*)&bias[col0 + tx * 4];
    const float bv[4] = {bb.x, bb.y, bb.z, bb.w};
#pragma unroll
    for (int i = 0; i < 4; ++i) {
        const int r = row0 + ty * 4 + i;
        float4 o;
        o.x = (c[i][0] + bv[0]) * scale;
        o.y = (c[i][1] + bv[1]) * scale;
        o.z = (c[i][2] + bv[2]) * scale;
        o.w = (c[i][3] + bv[3]) * scale;
        *(float4*)&out[(size_t)r * CD + col0 + tx * 4] = o;
    }
}

// qkv: z=0 -> q = (query@Wq.T + bq)*0.125 ; z=1 -> k ; z=2 -> v
__global__ __launch_bounds__(256) void qkv_gemm(const float* __restrict__ q_in,
                                                const float* __restrict__ k_in,
                                                const float* __restrict__ v_in,
                                                const float* __restrict__ W,
                                                const float* __restrict__ bias,
                                                float* __restrict__ ws) {
    const int z = blockIdx.z;
    const float* A = (z == 0) ? q_in : ((z == 1) ? k_in : v_in);
    gemm_nt_body(A, W + (size_t)z * CD * CD, bias + (size_t)z * CD,
                 ws + (size_t)z * NQ * CD, (z == 0) ? 0.125f : 1.0f);
}

__global__ __launch_bounds__(256) void out_gemm(const float* __restrict__ A,
                                                const float* __restrict__ W,
                                                const float* __restrict__ bias,
                                                float* __restrict__ out) {
    gemm_nt_body(A, W, bias, out, 1.0f);
}

// ---------------------------------------------------------------------------
// Attention: 1 block per query, 8 waves = 8 heads.
// Score phase: lane = (neighbor%4, dim-group) so each load instr covers 4
//   neighbors x 256B contiguous head-slices (16 fully-used lines/instr vs 64
//   scattered before). Partial dots reduced over the 16-lane group.
// Softmax: lane = neighbor, wave-wide shfl butterfly.
// PV: lane = dim, coalesced, branch-free, unrolled for load batching.
// XCD swizzle: consecutive j%8 -> same XCD gets one contiguous 1024-query
//   range = 2 batches = ~4MB of k+v slices, matching the 4MiB per-XCD L2.
// ---------------------------------------------------------------------------
__global__ __launch_bounds__(512) void attn_kernel(
    const float* __restrict__ ws_qkv,            // [q | k | v], each NQ*CD
    const int* __restrict__ index_pair,          // (NQ, LN)
    const int* __restrict__ key_batch_cnt,       // (BB,)
    const int* __restrict__ index_pair_batch,    // (NQ,)
    float* __restrict__ attn_out,                // NQ*CD (aliases q buffer)
    float* __restrict__ out2) {                  // NQ*LN
    const float* q_ws = ws_qkv;
    const float* k_ws = ws_qkv + (size_t)NQ * CD;
    const float* v_ws = ws_qkv + (size_t)2 * NQ * CD;

    const int j = blockIdx.x;
    const int n = (j & 7) * (NQ / 8) + (j >> 3);   // XCD-L2 locality swizzle

    const int tid  = threadIdx.x;
    const int h    = tid >> 6;     // wave id = head
    const int lane = tid & 63;

    __shared__ float qs[CD];
    __shared__ float wmat[HH][LN];
    __shared__ int   gs[LN];

    qs[tid] = q_ws[(size_t)n * CD + tid];

    if (tid < LN) {
        const int batch = index_pair_batch[n];
        int offset = 0;
        for (int b = 0; b < batch; ++b) offset += key_batch_cnt[b];
        const int gi = index_pair[n * LN + tid];
        gs[tid] = (gi >= 0) ? (gi + offset) : 0;   // reference safe-gather
    }
    __syncthreads();

    // --- scores: 4 neighbors per instr, 16 lanes x 4 dims each ------------
    const int r  = lane >> 4;      // neighbor within quad (0..3)
    const int dg = lane & 15;      // dim group (0..15) -> 4 dims
    const float4 q4 = *(const float4*)&qs[h * HD + dg * 4];
#pragma unroll
    for (int it = 0; it < 16; ++it) {
        const int l = it * 4 + r;
        const float4 k4 = *(const float4*)(k_ws + (size_t)gs[l] * CD + h * HD + dg * 4);
        float acc = k4.x * q4.x + k4.y * q4.y + k4.z * q4.z + k4.w * q4.w;
        acc += __shfl_xor(acc, 1, 64);
        acc += __shfl_xor(acc, 2, 64);
        acc += __shfl_xor(acc, 4, 64);
        acc += __shfl_xor(acc, 8, 64);
        if (dg == 0) wmat[h][l] = acc;
    }
    __syncthreads();

    // --- softmax over 64 lanes (lane = neighbor) --------------------------
    float score = wmat[h][lane];
    if (index_pair[n * LN + lane] < 0) score = -1000.0f;   // MASK_VAL
    float mx = score;
#pragma unroll
    for (int o = 32; o > 0; o >>= 1) mx = fmaxf(mx, __shfl_xor(mx, o, 64));
    float e = __expf(score - mx);           // masked lanes underflow to 0
    float s = e;
#pragma unroll
    for (int o = 32; o > 0; o >>= 1) s += __shfl_xor(s, o, 64);
    const float w = e / s;
    wmat[h][lane] = w;
    __syncthreads();

    // --- PV: lane = head-dim d, branch-free, batched loads ----------------
    float accv = 0.f;
#pragma unroll 8
    for (int l = 0; l < LN; ++l) {
        accv += wmat[h][l] * v_ws[(size_t)gs[l] * CD + h * HD + lane];
    }
    attn_out[(size_t)n * CD + tid] = accv;

    // --- output 2: sum over heads / H (wmat visible since pre-PV barrier) -
    if (tid < LN) {
        float s8 = 0.f;
#pragma unroll
        for (int hh = 0; hh < HH; ++hh) s8 += wmat[hh][tid];
        out2[(size_t)n * LN + tid] = s8 * (1.0f / HH);
    }
}

// ---------------------------------------------------------------------------
extern "C" void kernel_launch(void* const* d_in, const int* in_sizes, int n_in,
                              void* d_out, int out_size, void* d_ws, size_t ws_size,
                              hipStream_t stream) {
    const float* query   = (const float*)d_in[0];
    const float* key     = (const float*)d_in[1];
    const float* value   = (const float*)d_in[2];
    const float* ipw     = (const float*)d_in[3];   // (3C, C)
    const float* ipb     = (const float*)d_in[4];   // (3C,)
    const float* out_w   = (const float*)d_in[5];   // (C, C)
    const float* out_b   = (const float*)d_in[6];   // (C,)
    const int*   index_pair       = (const int*)d_in[7];
    // d_in[8] = query_batch_cnt (unused: implied by index_pair_batch)
    const int*   key_batch_cnt    = (const int*)d_in[9];
    const int*   index_pair_batch = (const int*)d_in[10];

    float* out = (float*)d_out;                // [attn (NQ*CD) | out2 (NQ*LN)]
    float* ws  = (float*)d_ws;                 // [q | k | v], 48 MB

    // 1) q/k/v projections
    dim3 g1(NQ / 64, CD / 64, 3);
    qkv_gemm<<<g1, 256, 0, stream>>>(query, key, value, ipw, ipb, ws);

    // 2) gather attention (attn overwrites q buffer in place) + output 2
    attn_kernel<<<NQ, 512, 0, stream>>>(ws, index_pair, key_batch_cnt,
                                        index_pair_batch, ws,
                                        out + (size_t)NQ * CD);

    // 3) out projection -> output 1
    dim3 g3(NQ / 64, CD / 64, 1);
    out_gemm<<<g3, 256, 0, stream>>>(ws, out_w, out_b, out);
}

// Round 3
// 284.132 us; speedup vs baseline: 2.0501x; 1.5335x over previous
//
#include <hip/hip_runtime.h>
#include <math.h>

#define NQ 8192   // queries
#define MK 8192   // keys
#define CD 512    // embed dim
#define LN 64     // neighbors per query
#define HH 8      // heads
#define HD 64     // head dim
#define BB 16     // batches

typedef short short8 __attribute__((ext_vector_type(8)));
typedef float floatx4 __attribute__((ext_vector_type(4)));

// fp32 -> bf16 RNE (inputs are normal values; NaN path irrelevant here)
__device__ __forceinline__ unsigned short f2bf(float x) {
    unsigned int u = __builtin_bit_cast(unsigned int, x);
    return (unsigned short)((u + 0x7FFFu + ((u >> 16) & 1u)) >> 16);
}
__device__ __forceinline__ unsigned int f2bf2(float lo, float hi) {
    return (unsigned int)f2bf(lo) | ((unsigned int)f2bf(hi) << 16);
}

// ---------------------------------------------------------------------------
// bf16-MFMA NT GEMM: out[i][j] = (sum_k A[i][k]*W[j][k] + bias[j]) * scale
// A: rows x CD fp32 row-major; W: CD x CD fp32 row-major (row j = out col j).
// 128x128 tile, BK=32, 256 threads = 4 waves (2x2), wave does 64x64 via
// 4x4 grid of 16x16x32 MFMA. fp32 loads converted inline to bf16 in LDS.
// LDS row stride 40 bf16 (80 B): ds_read_b128 lands 2 lanes/bank = free.
// ---------------------------------------------------------------------------
#define BK 32
#define LDST 40   // padded LDS row stride (bf16 units)

__device__ __forceinline__ void gemm_nt_mfma_body(const float* __restrict__ A,
                                                  const float* __restrict__ W,
                                                  const float* __restrict__ bias,
                                                  float* __restrict__ out,
                                                  float scale) {
    __shared__ unsigned short As[128 * LDST];
    __shared__ unsigned short Bs[128 * LDST];

    const int tid  = threadIdx.x;
    const int row0 = blockIdx.x * 128;
    const int col0 = blockIdx.y * 128;

    // staging map: thread t -> row t>>1 (0..127), k-half (t&1)*16
    const int srow = tid >> 1;
    const int kh   = (tid & 1) * 16;
    const float* Ap = A + (size_t)(row0 + srow) * CD + kh;
    const float* Wp = W + (size_t)(col0 + srow) * CD + kh;

    // wave map: 2x2 waves of 64x64
    const int w    = tid >> 6;
    const int wr   = w >> 1;
    const int wc   = w & 1;
    const int lane = tid & 63;
    const int q    = lane >> 4;    // quad
    const int ml   = lane & 15;

    floatx4 acc[4][4];
#pragma unroll
    for (int i = 0; i < 4; ++i)
#pragma unroll
        for (int j = 0; j < 4; ++j)
            acc[i][j] = (floatx4){0.f, 0.f, 0.f, 0.f};

    for (int k0 = 0; k0 < CD; k0 += BK) {
        // ---- stage fp32 -> bf16 into LDS (16 elems per thread per matrix)
        float4 a0 = *(const float4*)(Ap + k0 + 0);
        float4 a1 = *(const float4*)(Ap + k0 + 4);
        float4 a2 = *(const float4*)(Ap + k0 + 8);
        float4 a3 = *(const float4*)(Ap + k0 + 12);
        float4 b0 = *(const float4*)(Wp + k0 + 0);
        float4 b1 = *(const float4*)(Wp + k0 + 4);
        float4 b2 = *(const float4*)(Wp + k0 + 8);
        float4 b3 = *(const float4*)(Wp + k0 + 12);
        uint4 apk0, apk1, bpk0, bpk1;
        apk0.x = f2bf2(a0.x, a0.y); apk0.y = f2bf2(a0.z, a0.w);
        apk0.z = f2bf2(a1.x, a1.y); apk0.w = f2bf2(a1.z, a1.w);
        apk1.x = f2bf2(a2.x, a2.y); apk1.y = f2bf2(a2.z, a2.w);
        apk1.z = f2bf2(a3.x, a3.y); apk1.w = f2bf2(a3.z, a3.w);
        bpk0.x = f2bf2(b0.x, b0.y); bpk0.y = f2bf2(b0.z, b0.w);
        bpk0.z = f2bf2(b1.x, b1.y); bpk0.w = f2bf2(b1.z, b1.w);
        bpk1.x = f2bf2(b2.x, b2.y); bpk1.y = f2bf2(b2.z, b2.w);
        bpk1.z = f2bf2(b3.x, b3.y); bpk1.w = f2bf2(b3.z, b3.w);
        __syncthreads();   // protect previous iteration's fragment reads
        *(uint4*)&As[srow * LDST + kh + 0] = apk0;
        *(uint4*)&As[srow * LDST + kh + 8] = apk1;
        *(uint4*)&Bs[srow * LDST + kh + 0] = bpk0;
        *(uint4*)&Bs[srow * LDST + kh + 8] = bpk1;
        __syncthreads();

        // ---- fragments + MFMA (one 16x16x32 covers the whole BK)
        short8 af[4], bf[4];
#pragma unroll
        for (int mi = 0; mi < 4; ++mi)
            af[mi] = *(const short8*)&As[(wr * 64 + mi * 16 + ml) * LDST + q * 8];
#pragma unroll
        for (int ni = 0; ni < 4; ++ni)
            bf[ni] = *(const short8*)&Bs[(wc * 64 + ni * 16 + ml) * LDST + q * 8];
#pragma unroll
        for (int mi = 0; mi < 4; ++mi)
#pragma unroll
            for (int ni = 0; ni < 4; ++ni)
                acc[mi][ni] = __builtin_amdgcn_mfma_f32_16x16x32_bf16(
                    af[mi], bf[ni], acc[mi][ni], 0, 0, 0);
    }

    // ---- epilogue: D col = lane&15, row = quad*4 + reg
    float bv[4];
#pragma unroll
    for (int ni = 0; ni < 4; ++ni)
        bv[ni] = bias[col0 + wc * 64 + ni * 16 + ml];
#pragma unroll
    for (int mi = 0; mi < 4; ++mi) {
#pragma unroll
        for (int ni = 0; ni < 4; ++ni) {
            const int cg = col0 + wc * 64 + ni * 16 + ml;
#pragma unroll
            for (int r = 0; r < 4; ++r) {
                const int rg = row0 + wr * 64 + mi * 16 + q * 4 + r;
                out[(size_t)rg * CD + cg] = (acc[mi][ni][r] + bv[ni]) * scale;
            }
        }
    }
}

// qkv: z=0 -> q = (query@Wq.T + bq)*0.125 ; z=1 -> k ; z=2 -> v
__global__ __launch_bounds__(256) void qkv_gemm(const float* __restrict__ q_in,
                                                const float* __restrict__ k_in,
                                                const float* __restrict__ v_in,
                                                const float* __restrict__ W,
                                                const float* __restrict__ bias,
                                                float* __restrict__ ws) {
    const int z = blockIdx.z;
    const float* A = (z == 0) ? q_in : ((z == 1) ? k_in : v_in);
    gemm_nt_mfma_body(A, W + (size_t)z * CD * CD, bias + (size_t)z * CD,
                      ws + (size_t)z * NQ * CD, (z == 0) ? 0.125f : 1.0f);
}

__global__ __launch_bounds__(256) void out_gemm(const float* __restrict__ A,
                                                const float* __restrict__ W,
                                                const float* __restrict__ bias,
                                                float* __restrict__ out) {
    gemm_nt_mfma_body(A, W, bias, out, 1.0f);
}

// ---------------------------------------------------------------------------
// Attention: 1 block per query, 8 waves = 8 heads. (unchanged from R2)
// ---------------------------------------------------------------------------
__global__ __launch_bounds__(512) void attn_kernel(
    const float* __restrict__ ws_qkv,            // [q | k | v], each NQ*CD
    const int* __restrict__ index_pair,          // (NQ, LN)
    const int* __restrict__ key_batch_cnt,       // (BB,)
    const int* __restrict__ index_pair_batch,    // (NQ,)
    float* __restrict__ attn_out,                // NQ*CD (aliases q buffer)
    float* __restrict__ out2) {                  // NQ*LN
    const float* q_ws = ws_qkv;
    const float* k_ws = ws_qkv + (size_t)NQ * CD;
    const float* v_ws = ws_qkv + (size_t)2 * NQ * CD;

    const int j = blockIdx.x;
    const int n = (j & 7) * (NQ / 8) + (j >> 3);   // XCD-L2 locality swizzle

    const int tid  = threadIdx.x;
    const int h    = tid >> 6;     // wave id = head
    const int lane = tid & 63;

    __shared__ float qs[CD];
    __shared__ float wmat[HH][LN];
    __shared__ int   gs[LN];

    qs[tid] = q_ws[(size_t)n * CD + tid];

    if (tid < LN) {
        const int batch = index_pair_batch[n];
        int offset = 0;
        for (int b = 0; b < batch; ++b) offset += key_batch_cnt[b];
        const int gi = index_pair[n * LN + tid];
        gs[tid] = (gi >= 0) ? (gi + offset) : 0;   // reference safe-gather
    }
    __syncthreads();

    // --- scores: 4 neighbors per instr, 16 lanes x 4 dims each ------------
    const int r  = lane >> 4;      // neighbor within quad (0..3)
    const int dg = lane & 15;      // dim group (0..15) -> 4 dims
    const float4 q4 = *(const float4*)&qs[h * HD + dg * 4];
#pragma unroll
    for (int it = 0; it < 16; ++it) {
        const int l = it * 4 + r;
        const float4 k4 = *(const float4*)(k_ws + (size_t)gs[l] * CD + h * HD + dg * 4);
        float acc = k4.x * q4.x + k4.y * q4.y + k4.z * q4.z + k4.w * q4.w;
        acc += __shfl_xor(acc, 1, 64);
        acc += __shfl_xor(acc, 2, 64);
        acc += __shfl_xor(acc, 4, 64);
        acc += __shfl_xor(acc, 8, 64);
        if (dg == 0) wmat[h][l] = acc;
    }
    __syncthreads();

    // --- softmax over 64 lanes (lane = neighbor) --------------------------
    float score = wmat[h][lane];
    if (index_pair[n * LN + lane] < 0) score = -1000.0f;   // MASK_VAL
    float mx = score;
#pragma unroll
    for (int o = 32; o > 0; o >>= 1) mx = fmaxf(mx, __shfl_xor(mx, o, 64));
    float e = __expf(score - mx);           // masked lanes underflow to 0
    float s = e;
#pragma unroll
    for (int o = 32; o > 0; o >>= 1) s += __shfl_xor(s, o, 64);
    const float w = e / s;
    wmat[h][lane] = w;
    __syncthreads();

    // --- PV: lane = head-dim d, branch-free, batched loads ----------------
    float accv = 0.f;
#pragma unroll 8
    for (int l = 0; l < LN; ++l) {
        accv += wmat[h][l] * v_ws[(size_t)gs[l] * CD + h * HD + lane];
    }
    attn_out[(size_t)n * CD + tid] = accv;

    // --- output 2: sum over heads / H -------------------------------------
    if (tid < LN) {
        float s8 = 0.f;
#pragma unroll
        for (int hh = 0; hh < HH; ++hh) s8 += wmat[hh][tid];
        out2[(size_t)n * LN + tid] = s8 * (1.0f / HH);
    }
}

// ---------------------------------------------------------------------------
extern "C" void kernel_launch(void* const* d_in, const int* in_sizes, int n_in,
                              void* d_out, int out_size, void* d_ws, size_t ws_size,
                              hipStream_t stream) {
    const float* query   = (const float*)d_in[0];
    const float* key     = (const float*)d_in[1];
    const float* value   = (const float*)d_in[2];
    const float* ipw     = (const float*)d_in[3];   // (3C, C)
    const float* ipb     = (const float*)d_in[4];   // (3C,)
    const float* out_w   = (const float*)d_in[5];   // (C, C)
    const float* out_b   = (const float*)d_in[6];   // (C,)
    const int*   index_pair       = (const int*)d_in[7];
    // d_in[8] = query_batch_cnt (unused: implied by index_pair_batch)
    const int*   key_batch_cnt    = (const int*)d_in[9];
    const int*   index_pair_batch = (const int*)d_in[10];

    float* out = (float*)d_out;                // [attn (NQ*CD) | out2 (NQ*LN)]
    float* ws  = (float*)d_ws;                 // [q | k | v], 48 MB

    // 1) q/k/v projections (bf16 MFMA, fp32 out)
    dim3 g1(NQ / 128, CD / 128, 3);
    qkv_gemm<<<g1, 256, 0, stream>>>(query, key, value, ipw, ipb, ws);

    // 2) gather attention (attn overwrites q buffer in place) + output 2
    attn_kernel<<<NQ, 512, 0, stream>>>(ws, index_pair, key_batch_cnt,
                                        index_pair_batch, ws,
                                        out + (size_t)NQ * CD);

    // 3) out projection -> output 1
    dim3 g3(NQ / 128, CD / 128, 1);
    out_gemm<<<g3, 256, 0, stream>>>(ws, out_w, out_b, out);
}

// Round 5
// 245.852 us; speedup vs baseline: 2.3693x; 1.1557x over previous
//
#include <hip/hip_runtime.h>
#include <hip/hip_bf16.h>
#include <math.h>

#define NQ 8192   // queries
#define MK 8192   // keys
#define CD 512    // embed dim
#define LN 64     // neighbors per query
#define HH 8      // heads
#define HD 64     // head dim
#define BB 16     // batches

typedef short short8 __attribute__((ext_vector_type(8)));
typedef float floatx4 __attribute__((ext_vector_type(4)));

// fp32 -> bf16 RNE scalar (epilogue)
__device__ __forceinline__ unsigned short f2bf(float x) {
    unsigned int u = __builtin_bit_cast(unsigned int, x);
    return (unsigned short)((u + 0x7FFFu + ((u >> 16) & 1u)) >> 16);
}
// packed pair via HW v_cvt_pk_bf16_f32 on gfx950
__device__ __forceinline__ unsigned int pkbf(float lo, float hi) {
    float2 f; f.x = lo; f.y = hi;
    __hip_bfloat162 h2 = __float22bfloat162_rn(f);
    unsigned int u;
    __builtin_memcpy(&u, &h2, 4);
    return u;
}
// bf16 pair -> floats (shift/mask)
__device__ __forceinline__ float bflo(unsigned int u) {
    return __builtin_bit_cast(float, u << 16);
}
__device__ __forceinline__ float bfhi(unsigned int u) {
    return __builtin_bit_cast(float, u & 0xffff0000u);
}

// ---------------------------------------------------------------------------
// bf16-MFMA NT GEMM: val[i][j] = sum_k A[i][k]*W[j][k] + bias[j]
// out either fp32 (*scale) or bf16 (k/v for the gather-attention consumer).
// 128x128 tile, BK=32, 256 threads = 4 waves (2x2), wave = 64x64 via 4x4
// grid of 16x16x32 MFMA. Staging converts fp32->bf16 with v_cvt_pk_bf16_f32.
// ---------------------------------------------------------------------------
#define BK 32
#define LDST 40   // padded LDS row stride (bf16 units)

__device__ __forceinline__ void gemm_nt_mfma_body(const float* __restrict__ A,
                                                  const float* __restrict__ W,
                                                  const float* __restrict__ bias,
                                                  float* __restrict__ outf,
                                                  unsigned short* __restrict__ outb,
                                                  float scale) {
    __shared__ unsigned short As[128 * LDST];
    __shared__ unsigned short Bs[128 * LDST];

    const int tid  = threadIdx.x;
    const int row0 = blockIdx.x * 128;
    const int col0 = blockIdx.y * 128;

    // staging map: thread t -> row t>>1 (0..127), k-half (t&1)*16
    const int srow = tid >> 1;
    const int kh   = (tid & 1) * 16;
    const float* Ap = A + (size_t)(row0 + srow) * CD + kh;
    const float* Wp = W + (size_t)(col0 + srow) * CD + kh;

    // wave map: 2x2 waves of 64x64
    const int w    = tid >> 6;
    const int wr   = w >> 1;
    const int wc   = w & 1;
    const int lane = tid & 63;
    const int q    = lane >> 4;    // quad
    const int ml   = lane & 15;

    floatx4 acc[4][4];
#pragma unroll
    for (int i = 0; i < 4; ++i)
#pragma unroll
        for (int j = 0; j < 4; ++j)
            acc[i][j] = (floatx4){0.f, 0.f, 0.f, 0.f};

    for (int k0 = 0; k0 < CD; k0 += BK) {
        float4 a0 = *(const float4*)(Ap + k0 + 0);
        float4 a1 = *(const float4*)(Ap + k0 + 4);
        float4 a2 = *(const float4*)(Ap + k0 + 8);
        float4 a3 = *(const float4*)(Ap + k0 + 12);
        float4 b0 = *(const float4*)(Wp + k0 + 0);
        float4 b1 = *(const float4*)(Wp + k0 + 4);
        float4 b2 = *(const float4*)(Wp + k0 + 8);
        float4 b3 = *(const float4*)(Wp + k0 + 12);
        uint4 apk0, apk1, bpk0, bpk1;
        apk0.x = pkbf(a0.x, a0.y); apk0.y = pkbf(a0.z, a0.w);
        apk0.z = pkbf(a1.x, a1.y); apk0.w = pkbf(a1.z, a1.w);
        apk1.x = pkbf(a2.x, a2.y); apk1.y = pkbf(a2.z, a2.w);
        apk1.z = pkbf(a3.x, a3.y); apk1.w = pkbf(a3.z, a3.w);
        bpk0.x = pkbf(b0.x, b0.y); bpk0.y = pkbf(b0.z, b0.w);
        bpk0.z = pkbf(b1.x, b1.y); bpk0.w = pkbf(b1.z, b1.w);
        bpk1.x = pkbf(b2.x, b2.y); bpk1.y = pkbf(b2.z, b2.w);
        bpk1.z = pkbf(b3.x, b3.y); bpk1.w = pkbf(b3.z, b3.w);
        __syncthreads();   // protect previous iteration's fragment reads
        *(uint4*)&As[srow * LDST + kh + 0] = apk0;
        *(uint4*)&As[srow * LDST + kh + 8] = apk1;
        *(uint4*)&Bs[srow * LDST + kh + 0] = bpk0;
        *(uint4*)&Bs[srow * LDST + kh + 8] = bpk1;
        __syncthreads();

        short8 af[4], bf[4];
#pragma unroll
        for (int mi = 0; mi < 4; ++mi)
            af[mi] = *(const short8*)&As[(wr * 64 + mi * 16 + ml) * LDST + q * 8];
#pragma unroll
        for (int ni = 0; ni < 4; ++ni)
            bf[ni] = *(const short8*)&Bs[(wc * 64 + ni * 16 + ml) * LDST + q * 8];
#pragma unroll
        for (int mi = 0; mi < 4; ++mi)
#pragma unroll
            for (int ni = 0; ni < 4; ++ni)
                acc[mi][ni] = __builtin_amdgcn_mfma_f32_16x16x32_bf16(
                    af[mi], bf[ni], acc[mi][ni], 0, 0, 0);
    }

    // ---- epilogue: D col = lane&15, row = quad*4 + reg
    float bv[4];
#pragma unroll
    for (int ni = 0; ni < 4; ++ni)
        bv[ni] = bias[col0 + wc * 64 + ni * 16 + ml];
#pragma unroll
    for (int mi = 0; mi < 4; ++mi) {
#pragma unroll
        for (int ni = 0; ni < 4; ++ni) {
            const int cg = col0 + wc * 64 + ni * 16 + ml;
#pragma unroll
            for (int r = 0; r < 4; ++r) {
                const int rg = row0 + wr * 64 + mi * 16 + q * 4 + r;
                const float val = acc[mi][ni][r] + bv[ni];
                if (outb) outb[(size_t)rg * CD + cg] = f2bf(val);
                else      outf[(size_t)rg * CD + cg] = val * scale;
            }
        }
    }
}

// qkv: z=0 -> q fp32 = (query@Wq.T + bq)*0.125 ; z=1 -> k bf16 ; z=2 -> v bf16
__global__ __launch_bounds__(256) void qkv_gemm(const float* __restrict__ q_in,
                                                const float* __restrict__ k_in,
                                                const float* __restrict__ v_in,
                                                const float* __restrict__ W,
                                                const float* __restrict__ bias,
                                                float* __restrict__ q_ws,
                                                unsigned short* __restrict__ k_bf,
                                                unsigned short* __restrict__ v_bf) {
    const int z = blockIdx.z;
    const float* A = (z == 0) ? q_in : ((z == 1) ? k_in : v_in);
    float* outf = (z == 0) ? q_ws : nullptr;
    unsigned short* outb = (z == 1) ? k_bf : ((z == 2) ? v_bf : nullptr);
    gemm_nt_mfma_body(A, W + (size_t)z * CD * CD, bias + (size_t)z * CD,
                      outf, outb, 0.125f);
}

__global__ __launch_bounds__(256) void out_gemm(const float* __restrict__ A,
                                                const float* __restrict__ W,
                                                const float* __restrict__ bias,
                                                float* __restrict__ out) {
    gemm_nt_mfma_body(A, W, bias, out, nullptr, 1.0f);
}

// ---------------------------------------------------------------------------
// Attention, bf16 k/v: 1 block per query, 8 waves = 8 heads.
// Lane layout r=lane>>3 (neighbor in group of 8), dg=lane&7 (8 dims).
// One uint4 load = 8 bf16 dims; 8 iterations cover 64 neighbors.
// Gather byte-offsets computed once, shared by the k (score) and v (PV)
// phases. PV reduces over neighbor-group bits via shfl butterfly.
// ---------------------------------------------------------------------------
__global__ __launch_bounds__(512) void attn_kernel(
    const float* __restrict__ q_ws,              // NQ*CD fp32
    const unsigned short* __restrict__ k_bf,     // NQ*CD bf16
    const unsigned short* __restrict__ v_bf,     // NQ*CD bf16
    const int* __restrict__ index_pair,          // (NQ, LN)
    const int* __restrict__ key_batch_cnt,       // (BB,)
    const int* __restrict__ index_pair_batch,    // (NQ,)
    float* __restrict__ attn_out,                // NQ*CD fp32 (aliases q_ws)
    float* __restrict__ out2) {                  // NQ*LN
    const int j = blockIdx.x;
    const int n = (j & 7) * (NQ / 8) + (j >> 3);   // XCD-L2 locality swizzle

    const int tid  = threadIdx.x;
    const int h    = tid >> 6;     // wave id = head
    const int lane = tid & 63;
    const int r    = lane >> 3;    // neighbor within group (0..7)
    const int dg   = lane & 7;     // dim group (0..7) -> 8 dims

    __shared__ float qs[CD];
    __shared__ float wmat[HH][LN];
    __shared__ int   gs[LN];

    qs[tid] = q_ws[(size_t)n * CD + tid];

    if (tid < LN) {
        const int batch = index_pair_batch[n];
        int offset = 0;
        for (int b = 0; b < batch; ++b) offset += key_batch_cnt[b];
        const int gi = index_pair[n * LN + tid];
        gs[tid] = (gi >= 0) ? (gi + offset) : 0;   // reference safe-gather
    }
    __syncthreads();

    // q fragment: dims dg*8 .. dg*8+7 of head h
    float q8[8];
#pragma unroll
    for (int d = 0; d < 8; ++d) q8[d] = qs[h * HD + dg * 8 + d];

    // gather byte offsets (same for k and v): row*1024 + head*128 + dg*16
    unsigned int off[8];
#pragma unroll
    for (int it = 0; it < 8; ++it)
        off[it] = (unsigned int)gs[it * 8 + r] * (CD * 2) + h * (HD * 2) + dg * 16;

    // --- scores: 8 neighbors per instr, reduce over dg bits (1,2,4) -------
#pragma unroll
    for (int it = 0; it < 8; ++it) {
        const uint4 kv = *(const uint4*)((const char*)k_bf + off[it]);
        float acc;
        acc  = bflo(kv.x) * q8[0];
        acc  = fmaf(bfhi(kv.x), q8[1], acc);
        acc  = fmaf(bflo(kv.y), q8[2], acc);
        acc  = fmaf(bfhi(kv.y), q8[3], acc);
        acc  = fmaf(bflo(kv.z), q8[4], acc);
        acc  = fmaf(bfhi(kv.z), q8[5], acc);
        acc  = fmaf(bflo(kv.w), q8[6], acc);
        acc  = fmaf(bfhi(kv.w), q8[7], acc);
        acc += __shfl_xor(acc, 1, 64);
        acc += __shfl_xor(acc, 2, 64);
        acc += __shfl_xor(acc, 4, 64);
        if (dg == 0) wmat[h][it * 8 + r] = acc;
    }

    // --- softmax over 64 lanes (lane = neighbor; same-wave LDS RAW ok) ----
    float score = wmat[h][lane];
    if (index_pair[n * LN + lane] < 0) score = -1000.0f;   // MASK_VAL
    float mx = score;
#pragma unroll
    for (int o = 32; o > 0; o >>= 1) mx = fmaxf(mx, __shfl_xor(mx, o, 64));
    float e = __expf(score - mx);           // masked lanes underflow to 0
    float s = e;
#pragma unroll
    for (int o = 32; o > 0; o >>= 1) s += __shfl_xor(s, o, 64);
    const float w = e / s;
    wmat[h][lane] = w;
    __syncthreads();   // publish w for out2 (cross-wave read below)

    // --- PV: same layout, accumulate float[8], butterfly over r bits ------
    float a8[8] = {0.f, 0.f, 0.f, 0.f, 0.f, 0.f, 0.f, 0.f};
#pragma unroll
    for (int it = 0; it < 8; ++it) {
        const float wl = __shfl(w, it * 8 + r, 64);
        const uint4 vv = *(const uint4*)((const char*)v_bf + off[it]);
        a8[0] = fmaf(wl, bflo(vv.x), a8[0]);
        a8[1] = fmaf(wl, bfhi(vv.x), a8[1]);
        a8[2] = fmaf(wl, bflo(vv.y), a8[2]);
        a8[3] = fmaf(wl, bfhi(vv.y), a8[3]);
        a8[4] = fmaf(wl, bflo(vv.z), a8[4]);
        a8[5] = fmaf(wl, bfhi(vv.z), a8[5]);
        a8[6] = fmaf(wl, bflo(vv.w), a8[6]);
        a8[7] = fmaf(wl, bfhi(vv.w), a8[7]);
    }
#pragma unroll
    for (int o = 8; o <= 32; o <<= 1)
#pragma unroll
        for (int d = 0; d < 8; ++d) a8[d] += __shfl_xor(a8[d], o, 64);
    // lane (r,dg) stores dim dg*8+r (permuted within the 256B segment)
    attn_out[(size_t)n * CD + h * HD + dg * 8 + r] = a8[r];

    // --- output 2: sum over heads / H -------------------------------------
    if (tid < LN) {
        float s8 = 0.f;
#pragma unroll
        for (int hh = 0; hh < HH; ++hh) s8 += wmat[hh][tid];
        out2[(size_t)n * LN + tid] = s8 * (1.0f / HH);
    }
}

// ---------------------------------------------------------------------------
extern "C" void kernel_launch(void* const* d_in, const int* in_sizes, int n_in,
                              void* d_out, int out_size, void* d_ws, size_t ws_size,
                              hipStream_t stream) {
    const float* query   = (const float*)d_in[0];
    const float* key     = (const float*)d_in[1];
    const float* value   = (const float*)d_in[2];
    const float* ipw     = (const float*)d_in[3];   // (3C, C)
    const float* ipb     = (const float*)d_in[4];   // (3C,)
    const float* out_w   = (const float*)d_in[5];   // (C, C)
    const float* out_b   = (const float*)d_in[6];   // (C,)
    const int*   index_pair       = (const int*)d_in[7];
    // d_in[8] = query_batch_cnt (unused: implied by index_pair_batch)
    const int*   key_batch_cnt    = (const int*)d_in[9];
    const int*   index_pair_batch = (const int*)d_in[10];

    float* out = (float*)d_out;                // [attn (NQ*CD) | out2 (NQ*LN)]
    float* ws  = (float*)d_ws;
    float*          q_ws = ws;                                   // 16 MB fp32
    unsigned short* k_bf = (unsigned short*)(ws + (size_t)NQ * CD);  // 8 MB
    unsigned short* v_bf = k_bf + (size_t)NQ * CD;                   // 8 MB

    // 1) q/k/v projections (bf16 MFMA; q fp32, k/v bf16)
    dim3 g1(NQ / 128, CD / 128, 3);
    qkv_gemm<<<g1, 256, 0, stream>>>(query, key, value, ipw, ipb,
                                     q_ws, k_bf, v_bf);

    // 2) gather attention (attn overwrites q buffer in place) + output 2
    attn_kernel<<<NQ, 512, 0, stream>>>(q_ws, k_bf, v_bf, index_pair,
                                        key_batch_cnt, index_pair_batch,
                                        q_ws, out + (size_t)NQ * CD);

    // 3) out projection -> output 1
    dim3 g3(NQ / 128, CD / 128, 1);
    out_gemm<<<g3, 256, 0, stream>>>(q_ws, out_w, out_b, out);
}

// Round 6
// 230.939 us; speedup vs baseline: 2.5223x; 1.0646x over previous
//
#include <hip/hip_runtime.h>
#include <hip/hip_bf16.h>
#include <math.h>

#define NQ 8192   // queries
#define MK 8192   // keys
#define CD 512    // embed dim
#define LN 64     // neighbors per query
#define HH 8      // heads
#define HD 64     // head dim
#define BB 16     // batches

typedef short short8 __attribute__((ext_vector_type(8)));
typedef float floatx4 __attribute__((ext_vector_type(4)));

// fp32 -> bf16 RNE scalar
__device__ __forceinline__ unsigned short f2bf(float x) {
    unsigned int u = __builtin_bit_cast(unsigned int, x);
    return (unsigned short)((u + 0x7FFFu + ((u >> 16) & 1u)) >> 16);
}
// packed pair via HW v_cvt_pk_bf16_f32 on gfx950
__device__ __forceinline__ unsigned int pkbf(float lo, float hi) {
    float2 f; f.x = lo; f.y = hi;
    __hip_bfloat162 h2 = __float22bfloat162_rn(f);
    unsigned int u;
    __builtin_memcpy(&u, &h2, 4);
    return u;
}
// bf16 pair -> floats (shift/mask)
__device__ __forceinline__ float bflo(unsigned int u) {
    return __builtin_bit_cast(float, u << 16);
}
__device__ __forceinline__ float bfhi(unsigned int u) {
    return __builtin_bit_cast(float, u & 0xffff0000u);
}

// async global->LDS, 16B per lane; LDS dest = wave-uniform base + lane*16
__device__ __forceinline__ void gl_lds16(const unsigned short* g, unsigned short* l) {
    __builtin_amdgcn_global_load_lds(
        (const __attribute__((address_space(1))) unsigned int*)g,
        (__attribute__((address_space(3))) unsigned int*)l, 16, 0, 0);
}

// ---------------------------------------------------------------------------
// fp32 -> bf16 conversion prepass (5 segments in one launch)
// ---------------------------------------------------------------------------
struct ConvSeg { const float* src; unsigned short* dst; int n4; };
struct ConvArgs { ConvSeg s[5]; };

__global__ __launch_bounds__(256) void convert_bf16(ConvArgs a) {
    const int seg = blockIdx.y;
    const int i = blockIdx.x * 256 + threadIdx.x;
    if (i >= a.s[seg].n4) return;
    const float4 v = ((const float4*)a.s[seg].src)[i];
    uint2 o; o.x = pkbf(v.x, v.y); o.y = pkbf(v.z, v.w);
    ((uint2*)a.s[seg].dst)[i] = o;
}

// ---------------------------------------------------------------------------
// m97-style bf16 NT GEMM: val[i][j] = sum_k A[i][k]*W[j][k] + bias[j]
// A: rows x CD bf16 row-major; W: CD x CD bf16 row-major (row j = out col j).
// 128x128 tile, BK=64, 256 threads = 4 waves (2x2), wave = 64x64 via 4x4
// grid of 16x16x32 MFMA, 2 k-windows per iter.
// Staging: global_load_lds_dwordx4 (8 instrs/wave/iter, zero staging VALU).
// No LDS padding allowed (lane*16 dest) -> XOR-swizzle the SOURCE granule:
//   LDS[row][p] holds A[row][p ^ (row&7)]  (granules of 8 bf16 = 16B)
// so fragment ds_read_b128 at phys granule (glog ^ (row&7)) spreads the 16
// lanes sharing a quad across all 32 banks (2 lanes/bank = free, m136).
// ---------------------------------------------------------------------------
__device__ __forceinline__ void gemm_bf_body(const unsigned short* __restrict__ A,
                                             const unsigned short* __restrict__ W,
                                             const float* __restrict__ bias,
                                             float* __restrict__ outf,
                                             unsigned short* __restrict__ outb,
                                             float scale) {
    __shared__ unsigned short As[128 * 64];
    __shared__ unsigned short Bs[128 * 64];

    const int tid  = threadIdx.x;
    const int row0 = blockIdx.x * 128;
    const int col0 = blockIdx.y * 128;

    const int w    = tid >> 6;
    const int lane = tid & 63;
    const int wr   = w >> 1;
    const int wc   = w & 1;
    const int q    = lane >> 4;    // quad
    const int ml   = lane & 15;

    // staging: wave w covers rows [w*32, w*32+32), 4 instrs x 8 rows each.
    // lane L -> row offset (L>>3), phys granule (L&7); source granule XORed.
    const int sr = lane >> 3;            // 0..7 (== row&7 of the loaded row)
    const int sg = (lane & 7) ^ sr;      // logical granule this lane fetches
    const unsigned short* Ap = A + (size_t)(row0 + w * 32 + sr) * CD + sg * 8;
    const unsigned short* Wp = W + (size_t)(col0 + w * 32 + sr) * CD + sg * 8;
    unsigned short* Asw = &As[(w * 32) * 64];
    unsigned short* Bsw = &Bs[(w * 32) * 64];

    floatx4 acc[4][4];
#pragma unroll
    for (int i = 0; i < 4; ++i)
#pragma unroll
        for (int j = 0; j < 4; ++j)
            acc[i][j] = (floatx4){0.f, 0.f, 0.f, 0.f};

    for (int k0 = 0; k0 < CD; k0 += 64) {
        __syncthreads();   // previous iter's fragment reads done
#pragma unroll
        for (int i = 0; i < 4; ++i) {
            gl_lds16(Ap + (size_t)(i * 8) * CD + k0, Asw + i * 8 * 64);
            gl_lds16(Wp + (size_t)(i * 8) * CD + k0, Bsw + i * 8 * 64);
        }
        __syncthreads();   // drains vmcnt -> staged tile visible

#pragma unroll
        for (int kw = 0; kw < 2; ++kw) {
            short8 af[4], bf[4];
            const int gp = ((kw * 4 + q) ^ (ml & 7)) * 8;   // swizzled phys granule
#pragma unroll
            for (int mi = 0; mi < 4; ++mi)
                af[mi] = *(const short8*)&As[(wr * 64 + mi * 16 + ml) * 64 + gp];
#pragma unroll
            for (int ni = 0; ni < 4; ++ni)
                bf[ni] = *(const short8*)&Bs[(wc * 64 + ni * 16 + ml) * 64 + gp];
#pragma unroll
            for (int mi = 0; mi < 4; ++mi)
#pragma unroll
                for (int ni = 0; ni < 4; ++ni)
                    acc[mi][ni] = __builtin_amdgcn_mfma_f32_16x16x32_bf16(
                        af[mi], bf[ni], acc[mi][ni], 0, 0, 0);
        }
    }

    // ---- epilogue: D col = lane&15, row = quad*4 + reg
    float bv[4];
#pragma unroll
    for (int ni = 0; ni < 4; ++ni)
        bv[ni] = bias[col0 + wc * 64 + ni * 16 + ml];
#pragma unroll
    for (int mi = 0; mi < 4; ++mi) {
#pragma unroll
        for (int ni = 0; ni < 4; ++ni) {
            const int cg = col0 + wc * 64 + ni * 16 + ml;
#pragma unroll
            for (int r = 0; r < 4; ++r) {
                const int rg = row0 + wr * 64 + mi * 16 + q * 4 + r;
                const float val = acc[mi][ni][r] + bv[ni];
                if (outb) outb[(size_t)rg * CD + cg] = f2bf(val);
                else      outf[(size_t)rg * CD + cg] = val * scale;
            }
        }
    }
}

// qkv: z=0 -> q fp32 = (query@Wq.T + bq)*0.125 ; z=1 -> k bf16 ; z=2 -> v bf16
__global__ __launch_bounds__(256) void qkv_gemm(const unsigned short* __restrict__ A_bf,
                                                const unsigned short* __restrict__ w_bf,
                                                const float* __restrict__ bias,
                                                float* __restrict__ q_ws,
                                                unsigned short* __restrict__ k_bf,
                                                unsigned short* __restrict__ v_bf) {
    const int z = blockIdx.z;
    const unsigned short* A = A_bf + (size_t)z * NQ * CD;
    float* outf = (z == 0) ? q_ws : nullptr;
    unsigned short* outb = (z == 1) ? k_bf : ((z == 2) ? v_bf : nullptr);
    gemm_bf_body(A, w_bf + (size_t)z * CD * CD, bias + (size_t)z * CD,
                 outf, outb, 0.125f);
}

__global__ __launch_bounds__(256) void out_gemm(const unsigned short* __restrict__ A,
                                                const unsigned short* __restrict__ W,
                                                const float* __restrict__ bias,
                                                float* __restrict__ out) {
    gemm_bf_body(A, W, bias, out, nullptr, 1.0f);
}

// ---------------------------------------------------------------------------
// Attention, bf16 k/v: 1 block per query, 8 waves = 8 heads. (R5 structure;
// output now stored as bf16 for the bf16 out-projection GEMM.)
// ---------------------------------------------------------------------------
__global__ __launch_bounds__(512) void attn_kernel(
    const float* __restrict__ q_ws,              // NQ*CD fp32
    const unsigned short* __restrict__ k_bf,     // NQ*CD bf16
    const unsigned short* __restrict__ v_bf,     // NQ*CD bf16
    const int* __restrict__ index_pair,          // (NQ, LN)
    const int* __restrict__ key_batch_cnt,       // (BB,)
    const int* __restrict__ index_pair_batch,    // (NQ,)
    unsigned short* __restrict__ attn_bf,        // NQ*CD bf16
    float* __restrict__ out2) {                  // NQ*LN
    const int j = blockIdx.x;
    const int n = (j & 7) * (NQ / 8) + (j >> 3);   // XCD-L2 locality swizzle

    const int tid  = threadIdx.x;
    const int h    = tid >> 6;     // wave id = head
    const int lane = tid & 63;
    const int r    = lane >> 3;    // neighbor within group (0..7)
    const int dg   = lane & 7;     // dim group (0..7) -> 8 dims

    __shared__ float qs[CD];
    __shared__ float wmat[HH][LN];
    __shared__ int   gs[LN];

    qs[tid] = q_ws[(size_t)n * CD + tid];

    if (tid < LN) {
        const int batch = index_pair_batch[n];
        int offset = 0;
        for (int b = 0; b < batch; ++b) offset += key_batch_cnt[b];
        const int gi = index_pair[n * LN + tid];
        gs[tid] = (gi >= 0) ? (gi + offset) : 0;   // reference safe-gather
    }
    __syncthreads();

    // q fragment: dims dg*8 .. dg*8+7 of head h
    float q8[8];
#pragma unroll
    for (int d = 0; d < 8; ++d) q8[d] = qs[h * HD + dg * 8 + d];

    // gather byte offsets (same for k and v): row*1024 + head*128 + dg*16
    unsigned int off[8];
#pragma unroll
    for (int it = 0; it < 8; ++it)
        off[it] = (unsigned int)gs[it * 8 + r] * (CD * 2) + h * (HD * 2) + dg * 16;

    // --- scores: 8 neighbors per instr, reduce over dg bits (1,2,4) -------
#pragma unroll
    for (int it = 0; it < 8; ++it) {
        const uint4 kv = *(const uint4*)((const char*)k_bf + off[it]);
        float acc;
        acc  = bflo(kv.x) * q8[0];
        acc  = fmaf(bfhi(kv.x), q8[1], acc);
        acc  = fmaf(bflo(kv.y), q8[2], acc);
        acc  = fmaf(bfhi(kv.y), q8[3], acc);
        acc  = fmaf(bflo(kv.z), q8[4], acc);
        acc  = fmaf(bfhi(kv.z), q8[5], acc);
        acc  = fmaf(bflo(kv.w), q8[6], acc);
        acc  = fmaf(bfhi(kv.w), q8[7], acc);
        acc += __shfl_xor(acc, 1, 64);
        acc += __shfl_xor(acc, 2, 64);
        acc += __shfl_xor(acc, 4, 64);
        if (dg == 0) wmat[h][it * 8 + r] = acc;
    }

    // --- softmax over 64 lanes (lane = neighbor; same-wave LDS RAW ok) ----
    float score = wmat[h][lane];
    if (index_pair[n * LN + lane] < 0) score = -1000.0f;   // MASK_VAL
    float mx = score;
#pragma unroll
    for (int o = 32; o > 0; o >>= 1) mx = fmaxf(mx, __shfl_xor(mx, o, 64));
    float e = __expf(score - mx);           // masked lanes underflow to 0
    float s = e;
#pragma unroll
    for (int o = 32; o > 0; o >>= 1) s += __shfl_xor(s, o, 64);
    const float w = e / s;
    wmat[h][lane] = w;
    __syncthreads();   // publish w for out2 (cross-wave read below)

    // --- PV: same layout, accumulate float[8], butterfly over r bits ------
    float a8[8] = {0.f, 0.f, 0.f, 0.f, 0.f, 0.f, 0.f, 0.f};
#pragma unroll
    for (int it = 0; it < 8; ++it) {
        const float wl = __shfl(w, it * 8 + r, 64);
        const uint4 vv = *(const uint4*)((const char*)v_bf + off[it]);
        a8[0] = fmaf(wl, bflo(vv.x), a8[0]);
        a8[1] = fmaf(wl, bfhi(vv.x), a8[1]);
        a8[2] = fmaf(wl, bflo(vv.y), a8[2]);
        a8[3] = fmaf(wl, bfhi(vv.y), a8[3]);
        a8[4] = fmaf(wl, bflo(vv.z), a8[4]);
        a8[5] = fmaf(wl, bfhi(vv.z), a8[5]);
        a8[6] = fmaf(wl, bflo(vv.w), a8[6]);
        a8[7] = fmaf(wl, bfhi(vv.w), a8[7]);
    }
#pragma unroll
    for (int o = 8; o <= 32; o <<= 1)
#pragma unroll
        for (int d = 0; d < 8; ++d) a8[d] += __shfl_xor(a8[d], o, 64);
    // lane (r,dg) stores dim dg*8+r (permuted within the 256B segment)
    attn_bf[(size_t)n * CD + h * HD + dg * 8 + r] = f2bf(a8[r]);

    // --- output 2: sum over heads / H -------------------------------------
    if (tid < LN) {
        float s8 = 0.f;
#pragma unroll
        for (int hh = 0; hh < HH; ++hh) s8 += wmat[hh][tid];
        out2[(size_t)n * LN + tid] = s8 * (1.0f / HH);
    }
}

// ---------------------------------------------------------------------------
extern "C" void kernel_launch(void* const* d_in, const int* in_sizes, int n_in,
                              void* d_out, int out_size, void* d_ws, size_t ws_size,
                              hipStream_t stream) {
    const float* query   = (const float*)d_in[0];
    const float* key     = (const float*)d_in[1];
    const float* value   = (const float*)d_in[2];
    const float* ipw     = (const float*)d_in[3];   // (3C, C)
    const float* ipb     = (const float*)d_in[4];   // (3C,)
    const float* out_w   = (const float*)d_in[5];   // (C, C)
    const float* out_b   = (const float*)d_in[6];   // (C,)
    const int*   index_pair       = (const int*)d_in[7];
    // d_in[8] = query_batch_cnt (unused: implied by index_pair_batch)
    const int*   key_batch_cnt    = (const int*)d_in[9];
    const int*   index_pair_batch = (const int*)d_in[10];

    float* out = (float*)d_out;                // [attn (NQ*CD) | out2 (NQ*LN)]
    float* ws  = (float*)d_ws;
    // layout: q fp32 16MB | k_bf 8 | v_bf 8 | A_bf 24 (q|k|v inputs) | W_bf 2
    float*          q_ws  = ws;
    unsigned short* k_bf  = (unsigned short*)(ws + (size_t)NQ * CD);
    unsigned short* v_bf  = k_bf + (size_t)NQ * CD;
    unsigned short* A_bf  = v_bf + (size_t)NQ * CD;        // 3 * NQ*CD
    unsigned short* w_bf  = A_bf + (size_t)3 * NQ * CD;    // 3 * CD*CD (ipw)
    unsigned short* ow_bf = w_bf + (size_t)3 * CD * CD;    // CD*CD (out_w)
    // attn output (bf16) reuses the A_bf query slot (read-before-write order)
    unsigned short* attn_bf = A_bf;

    // 0) convert inputs/weights to bf16
    ConvArgs ca;
    ca.s[0] = {query, A_bf,                      NQ * CD / 4};
    ca.s[1] = {key,   A_bf + (size_t)NQ * CD,    NQ * CD / 4};
    ca.s[2] = {value, A_bf + (size_t)2 * NQ * CD, NQ * CD / 4};
    ca.s[3] = {ipw,   w_bf,                      3 * CD * CD / 4};
    ca.s[4] = {out_w, ow_bf,                     CD * CD / 4};
    dim3 g0(NQ * CD / 4 / 256, 5);
    convert_bf16<<<g0, 256, 0, stream>>>(ca);

    // 1) q/k/v projections (bf16-in MFMA; q fp32, k/v bf16)
    dim3 g1(NQ / 128, CD / 128, 3);
    qkv_gemm<<<g1, 256, 0, stream>>>(A_bf, w_bf, ipb, q_ws, k_bf, v_bf);

    // 2) gather attention -> bf16 attn + output 2
    attn_kernel<<<NQ, 512, 0, stream>>>(q_ws, k_bf, v_bf, index_pair,
                                        key_batch_cnt, index_pair_batch,
                                        attn_bf, out + (size_t)NQ * CD);

    // 3) out projection -> output 1
    dim3 g3(NQ / 128, CD / 128, 1);
    out_gemm<<<g3, 256, 0, stream>>>(attn_bf, ow_bf, out_b, out);
}